// Round 6
// baseline (861.376 us; speedup 1.0000x reference)
//
#include <hip/hip_runtime.h>
#include <math.h>

#define BB 4096
#define HH 2048
#define NBK 4
#define HB 512

typedef short bh8 __attribute__((ext_vector_type(8)));
typedef float f32x4 __attribute__((ext_vector_type(4)));
typedef unsigned int u32;

__device__ __forceinline__ float gelu_exact(float v) {
    return 0.5f * v * (1.0f + erff(v * 0.70710678118654752f));
}

// 8 fp32 -> 8 bf16 hi (truncate) + 8 bf16 lo (residual, truncate), packed u32x4 each.
__device__ __forceinline__ void cvt8(const float4 f0, const float4 f1,
                                     uint4& H, uint4& L) {
    u32 u0 = __float_as_uint(f0.x), u1 = __float_as_uint(f0.y),
        u2 = __float_as_uint(f0.z), u3 = __float_as_uint(f0.w),
        u4 = __float_as_uint(f1.x), u5 = __float_as_uint(f1.y),
        u6 = __float_as_uint(f1.z), u7 = __float_as_uint(f1.w);
    H.x = (u1 & 0xFFFF0000u) | (u0 >> 16);
    H.y = (u3 & 0xFFFF0000u) | (u2 >> 16);
    H.z = (u5 & 0xFFFF0000u) | (u4 >> 16);
    H.w = (u7 & 0xFFFF0000u) | (u6 >> 16);
    float l0 = f0.x - __uint_as_float(u0 & 0xFFFF0000u);
    float l1 = f0.y - __uint_as_float(u1 & 0xFFFF0000u);
    float l2 = f0.z - __uint_as_float(u2 & 0xFFFF0000u);
    float l3 = f0.w - __uint_as_float(u3 & 0xFFFF0000u);
    float l4 = f1.x - __uint_as_float(u4 & 0xFFFF0000u);
    float l5 = f1.y - __uint_as_float(u5 & 0xFFFF0000u);
    float l6 = f1.z - __uint_as_float(u6 & 0xFFFF0000u);
    float l7 = f1.w - __uint_as_float(u7 & 0xFFFF0000u);
    u32 v0 = __float_as_uint(l0), v1 = __float_as_uint(l1),
        v2 = __float_as_uint(l2), v3 = __float_as_uint(l3),
        v4 = __float_as_uint(l4), v5 = __float_as_uint(l5),
        v6 = __float_as_uint(l6), v7 = __float_as_uint(l7);
    L.x = (v1 & 0xFFFF0000u) | (v0 >> 16);
    L.y = (v3 & 0xFFFF0000u) | (v2 >> 16);
    L.z = (v5 & 0xFFFF0000u) | (v4 >> 16);
    L.w = (v7 & 0xFFFF0000u) | (v6 >> 16);
}

// A-side staging: convert + store into swizzled 64B-row LDS (r2-proven layout).
__device__ __forceinline__ void cvt_store(char* hiB, char* loB, int row, int cb,
                                          float4 f0, float4 f1) {
    uint4 H, L;
    cvt8(f0, f1, H, L);
    const int s = (cb ^ ((row >> 1) & 3)) * 16;
    *(uint4*)(hiB + row * 64 + s) = H;
    *(uint4*)(loB + row * 64 + s) = L;
}

// async 16B global->LDS (dest = wave-uniform base + lane*16)
__device__ __forceinline__ void gload_lds16(const u32* g, char* l) {
    __builtin_amdgcn_global_load_lds(
        (const __attribute__((address_space(1))) u32*)g,
        (__attribute__((address_space(3))) u32*)l, 16, 0, 0);
}

// Pack fp32 weight [N][K] row-major -> per (row, 32k-block): 128 B = 32 bf16 hi | 32 bf16 lo.
// One thread per 8 elements. rowShift = log2(K/8).
__global__ void pack_w(const float* __restrict__ W, u32* __restrict__ P,
                       int N, int K, int rowShift)
{
    const int idx = blockIdx.x * 256 + threadIdx.x;
    if (idx >= (N << rowShift)) return;
    const int n   = idx >> rowShift;
    const int rem = idx & ((1 << rowShift) - 1);
    const int t   = rem >> 2;
    const int g   = rem & 3;
    const float* src = W + (long)n * K + t * 32 + g * 8;
    uint4 H, L;
    cvt8(*(const float4*)src, *(const float4*)(src + 4), H, L);
    u32* blk = P + ((long)n * (K >> 5) + t) * 32;
    *(uint4*)(blk + g * 4)      = H;
    *(uint4*)(blk + 16 + g * 4) = L;
}

// C[M,N] = A[M,K(=HH)] @ B[N,K]^T, A fp32 (fused hi/lo cvt staging, r2-proven),
// B pre-packed bf16 hi/lo staged via global_load_lds into swizzled 128B rows.
// 128x128 tile, BK=32, 4 waves. Two barriers per K-tile (r2 structure).
template<int EPI>
__global__ __launch_bounds__(256, 2)
void bgemm_pw(const float* __restrict__ A,
              const u32* __restrict__ Bp,   // packed [N][K/32][128B]
              float* __restrict__ C)
{
    __shared__ uint4 ldsv[3072];             // 48 KB
    char* lds = (char*)ldsv;
    char* Ah = lds;                          // 8 KB  [128][64B] swizzled
    char* Al = lds + 8192;                   // 8 KB
    char* B0 = lds + 16384;                  // 16 KB [128][128B] swizzled (dbuf)
    char* B1 = lds + 32768;                  // 16 KB

    const int tid  = threadIdx.x;
    const int row0 = blockIdx.y * 128;
    const int col0 = blockIdx.x * 128;

    const int sr  = tid >> 2;
    const int scb = tid & 3;
    const float* Ald = A + (long)(row0 + sr) * HH + scb * 8;
    const long a64 = 64L * HH;

    const int lane = tid & 63;
    const int w    = tid >> 6;
    const int wr = (tid >> 7) & 1;
    const int wc = (tid >> 6) & 1;
    const int fm = lane & 15;
    const int kb = lane >> 4;
    const int fr7 = fm & 7;

    // A fragment offsets (r2-proven)
    const int aslot = ((kb ^ ((fm >> 1) & 3)) & 3) * 16;
    const int aoff  = (wr * 64 + fm) * 64 + aslot;
    // B fragment offsets: row r=wc*64+j*16+fm, phys slot = logical ^ (r&7)
    const int bbase  = (wc * 64 + fm) * 128;
    const int bhioff = bbase + ((kb ^ fr7) * 16);         // + j*2048
    const int blooff = bbase + (((4 | kb) ^ fr7) * 16);   // + j*2048

    // B gload: wave w stages rows w*32..+31 in 4 insts of 8 rows.
    // dest linear (base+lane*16); source pre-swizzled: s_log = (lane&7)^(lane>>3)
    const int lrow8 = lane >> 3;
    const int slog  = (lane & 7) ^ lrow8;
    const int rloc  = w * 32;
    const u32* bsrc[4];
    #pragma unroll
    for (int i = 0; i < 4; ++i)
        bsrc[i] = Bp + ((long)(col0 + rloc + i * 8 + lrow8) * (HH / 32)) * 32 + slog * 4;

    f32x4 acc[4][4] = {};

    float4 p0 = *(const float4*)(Ald),       p1 = *(const float4*)(Ald + 4);
    float4 p2 = *(const float4*)(Ald + a64), p3 = *(const float4*)(Ald + a64 + 4);
    #pragma unroll
    for (int i = 0; i < 4; ++i)
        gload_lds16(bsrc[i], B0 + (rloc + i * 8) * 128);

    const int nkt = HH / 32;
    for (int kt = 0; kt < nkt; ++kt) {
        __syncthreads();                      // readers of prev LDS done; drains vmem
        cvt_store(Ah, Al, sr,      scb, p0, p1);
        cvt_store(Ah, Al, sr + 64, scb, p2, p3);
        __syncthreads();                      // A(kt) visible; B(kt) landed at bar1
        if (kt + 1 < nkt) {
            const float* pa = Ald + (kt + 1) * 32;
            p0 = *(const float4*)(pa);        p1 = *(const float4*)(pa + 4);
            p2 = *(const float4*)(pa + a64);  p3 = *(const float4*)(pa + a64 + 4);
            char* Bn = (kt & 1) ? B0 : B1;    // (kt+1)&1 buffer
            #pragma unroll
            for (int i = 0; i < 4; ++i)
                gload_lds16(bsrc[i] + (kt + 1) * 32, Bn + (rloc + i * 8) * 128);
        }
        const char* Bc = (kt & 1) ? B1 : B0;
        bh8 ahf[4], alf[4];
        #pragma unroll
        for (int i = 0; i < 4; ++i) {
            ahf[i] = *(const bh8*)(Ah + aoff + i * 1024);
            alf[i] = *(const bh8*)(Al + aoff + i * 1024);
        }
        #pragma unroll
        for (int j = 0; j < 4; ++j) {
            const bh8 bhf = *(const bh8*)(Bc + bhioff + j * 2048);
            const bh8 blf = *(const bh8*)(Bc + blooff + j * 2048);
            #pragma unroll
            for (int i = 0; i < 4; ++i)
                acc[i][j] = __builtin_amdgcn_mfma_f32_16x16x32_bf16(ahf[i], bhf, acc[i][j], 0, 0, 0);
            #pragma unroll
            for (int i = 0; i < 4; ++i)
                acc[i][j] = __builtin_amdgcn_mfma_f32_16x16x32_bf16(ahf[i], blf, acc[i][j], 0, 0, 0);
            #pragma unroll
            for (int i = 0; i < 4; ++i)
                acc[i][j] = __builtin_amdgcn_mfma_f32_16x16x32_bf16(alf[i], bhf, acc[i][j], 0, 0, 0);
        }
    }

    // D col = lane&15, row = (lane>>4)*4 + reg (verified m89 layout)
    const int erow = row0 + wr * 64 + (lane >> 4) * 4;
    const int ecol = col0 + wc * 64 + fm;
    #pragma unroll
    for (int i = 0; i < 4; ++i)
        #pragma unroll
        for (int j = 0; j < 4; ++j)
            #pragma unroll
            for (int r = 0; r < 4; ++r) {
                float v = acc[i][j][r];
                if (EPI == 1) v = gelu_exact(v);
                C[(long)(erow + i * 16 + r) * HH + ecol + j * 16] = v;
            }
}

// Fused blockdiag(Wi)+blockdiag(Wrg)+RG-LRU. A=xc fp32 (fused cvt staging);
// Wi/Wrg pre-packed, staged via global_load_lds (double-buffered).
// Grid: (HB/128, BB/128, NBK).
__global__ __launch_bounds__(256, 2)
void bd_rglru(const float* __restrict__ xc,
              const u32* __restrict__ Wip,   // packed [NBK*HB][HB/32][128B]
              const u32* __restrict__ Wrp,
              const float* __restrict__ rg,
              const float* gate,             // aliases hbuf (per-element r/w)
              const float* __restrict__ av,
              float* __restrict__ nrs,
              float* hbuf)
{
    __shared__ uint4 ldsv[5120];             // 80 KB
    char* lds = (char*)ldsv;
    char* Ah = lds;            char* Al = lds + 8192;
    char* I0 = lds + 16384;    char* I1 = lds + 32768;
    char* R0 = lds + 49152;    char* R1 = lds + 65536;

    const int nb   = blockIdx.z;
    const int tid  = threadIdx.x;
    const int row0 = blockIdx.y * 128;
    const int col0 = blockIdx.x * 128;

    const int sr  = tid >> 2;
    const int scb = tid & 3;
    const float* Ald = xc + (long)(row0 + sr) * HH + nb * HB + scb * 8;
    const long a64 = 64L * HH;

    const int lane = tid & 63;
    const int w    = tid >> 6;
    const int wr = (tid >> 7) & 1;
    const int wc = (tid >> 6) & 1;
    const int fm = lane & 15;
    const int kb = lane >> 4;
    const int fr7 = fm & 7;

    const int aslot = ((kb ^ ((fm >> 1) & 3)) & 3) * 16;
    const int aoff  = (wr * 64 + fm) * 64 + aslot;
    const int bbase  = (wc * 64 + fm) * 128;
    const int bhioff = bbase + ((kb ^ fr7) * 16);
    const int blooff = bbase + (((4 | kb) ^ fr7) * 16);

    const int lrow8 = lane >> 3;
    const int slog  = (lane & 7) ^ lrow8;
    const int rloc  = w * 32;
    const u32* isrc[4];
    const u32* rsrc[4];
    #pragma unroll
    for (int i = 0; i < 4; ++i) {
        const long nrow = (long)(nb * HB + col0 + rloc + i * 8 + lrow8) * (HB / 32);
        isrc[i] = Wip + nrow * 32 + slog * 4;
        rsrc[i] = Wrp + nrow * 32 + slog * 4;
    }

    f32x4 ai[4][4] = {}, ar[4][4] = {};

    float4 p0 = *(const float4*)(Ald),       p1 = *(const float4*)(Ald + 4);
    float4 p2 = *(const float4*)(Ald + a64), p3 = *(const float4*)(Ald + a64 + 4);
    #pragma unroll
    for (int i = 0; i < 4; ++i) {
        gload_lds16(isrc[i], I0 + (rloc + i * 8) * 128);
        gload_lds16(rsrc[i], R0 + (rloc + i * 8) * 128);
    }

    const int nkt = HB / 32;
    for (int kt = 0; kt < nkt; ++kt) {
        __syncthreads();
        cvt_store(Ah, Al, sr,      scb, p0, p1);
        cvt_store(Ah, Al, sr + 64, scb, p2, p3);
        __syncthreads();
        if (kt + 1 < nkt) {
            const float* pa = Ald + (kt + 1) * 32;
            p0 = *(const float4*)(pa);        p1 = *(const float4*)(pa + 4);
            p2 = *(const float4*)(pa + a64);  p3 = *(const float4*)(pa + a64 + 4);
            char* In = (kt & 1) ? I0 : I1;
            char* Rn = (kt & 1) ? R0 : R1;
            #pragma unroll
            for (int i = 0; i < 4; ++i) {
                gload_lds16(isrc[i] + (kt + 1) * 32, In + (rloc + i * 8) * 128);
                gload_lds16(rsrc[i] + (kt + 1) * 32, Rn + (rloc + i * 8) * 128);
            }
        }
        const char* Ic = (kt & 1) ? I1 : I0;
        const char* Rc = (kt & 1) ? R1 : R0;
        bh8 ahf[4], alf[4];
        #pragma unroll
        for (int i = 0; i < 4; ++i) {
            ahf[i] = *(const bh8*)(Ah + aoff + i * 1024);
            alf[i] = *(const bh8*)(Al + aoff + i * 1024);
        }
        #pragma unroll
        for (int j = 0; j < 4; ++j) {
            const bh8 bihf = *(const bh8*)(Ic + bhioff + j * 2048);
            const bh8 bilf = *(const bh8*)(Ic + blooff + j * 2048);
            const bh8 brhf = *(const bh8*)(Rc + bhioff + j * 2048);
            const bh8 brlf = *(const bh8*)(Rc + blooff + j * 2048);
            #pragma unroll
            for (int i = 0; i < 4; ++i)
                ai[i][j] = __builtin_amdgcn_mfma_f32_16x16x32_bf16(ahf[i], bihf, ai[i][j], 0, 0, 0);
            #pragma unroll
            for (int i = 0; i < 4; ++i)
                ai[i][j] = __builtin_amdgcn_mfma_f32_16x16x32_bf16(ahf[i], bilf, ai[i][j], 0, 0, 0);
            #pragma unroll
            for (int i = 0; i < 4; ++i)
                ai[i][j] = __builtin_amdgcn_mfma_f32_16x16x32_bf16(alf[i], bihf, ai[i][j], 0, 0, 0);
            #pragma unroll
            for (int i = 0; i < 4; ++i)
                ar[i][j] = __builtin_amdgcn_mfma_f32_16x16x32_bf16(ahf[i], brhf, ar[i][j], 0, 0, 0);
            #pragma unroll
            for (int i = 0; i < 4; ++i)
                ar[i][j] = __builtin_amdgcn_mfma_f32_16x16x32_bf16(ahf[i], brlf, ar[i][j], 0, 0, 0);
            #pragma unroll
            for (int i = 0; i < 4; ++i)
                ar[i][j] = __builtin_amdgcn_mfma_f32_16x16x32_bf16(alf[i], brhf, ar[i][j], 0, 0, 0);
        }
    }

    // RG-LRU epilogue (verified math)
    const int erow = row0 + wr * 64 + (lane >> 4) * 4;
    const int ecolL = col0 + wc * 64 + fm;
    #pragma unroll
    for (int j = 0; j < 4; ++j) {
        const int gcol = nb * HB + ecolL + j * 16;
        const float la8 = 8.0f * logf(av[gcol]);
        #pragma unroll
        for (int i = 0; i < 4; ++i)
            #pragma unroll
            for (int r = 0; r < 4; ++r) {
                const long off = (long)(erow + i * 16 + r) * HH + gcol;
                const float it = 1.0f / (1.0f + expf(-ai[i][j][r]));
                const float rt = 1.0f / (1.0f + expf(-ar[i][j][r]));
                const float at = expf(la8 * rt);
                const float mult = sqrtf(fmaxf(0.0f, 1.0f - at * at));
                const float o = fmaf(rg[off], at, mult * (it * xc[off]));
                nrs[off]  = o;
                hbuf[off] = gate[off] * o;
            }
    }
}

// xc = sum_k window[b,k,h]*conv_w[k,h] + conv_b[h]; shifts conv_state.
// In-place: xcio holds xr on entry, xc on exit (per-element read-then-write).
__global__ void conv_kernel(const float* __restrict__ cs,   // [B,3,H]
                            const float* __restrict__ cw,   // [4,H]
                            const float* __restrict__ cb,   // [H]
                            float* xcio,                    // [B,H] xr -> xc
                            float* __restrict__ ncs)        // [B,3,H]
{
    const long idx = (long)blockIdx.x * blockDim.x + threadIdx.x;
    const long n4 = (long)BB * HH / 4;
    if (idx >= n4) return;
    const long b = idx / (HH / 4);
    const int  h = (int)(idx % (HH / 4)) * 4;

    const float4 c0 = *(const float4*)&cs[(b * 3 + 0) * HH + h];
    const float4 c1 = *(const float4*)&cs[(b * 3 + 1) * HH + h];
    const float4 c2 = *(const float4*)&cs[(b * 3 + 2) * HH + h];
    const float4 xv = *(const float4*)&xcio[b * HH + h];
    const float4 w0 = *(const float4*)&cw[0 * HH + h];
    const float4 w1 = *(const float4*)&cw[1 * HH + h];
    const float4 w2 = *(const float4*)&cw[2 * HH + h];
    const float4 w3 = *(const float4*)&cw[3 * HH + h];
    const float4 bb = *(const float4*)&cb[h];

    float4 r;
    r.x = fmaf(c0.x, w0.x, fmaf(c1.x, w1.x, fmaf(c2.x, w2.x, fmaf(xv.x, w3.x, bb.x))));
    r.y = fmaf(c0.y, w0.y, fmaf(c1.y, w1.y, fmaf(c2.y, w2.y, fmaf(xv.y, w3.y, bb.y))));
    r.z = fmaf(c0.z, w0.z, fmaf(c1.z, w1.z, fmaf(c2.z, w2.z, fmaf(xv.z, w3.z, bb.z))));
    r.w = fmaf(c0.w, w0.w, fmaf(c1.w, w1.w, fmaf(c2.w, w2.w, fmaf(xv.w, w3.w, bb.w))));

    *(float4*)&xcio[b * HH + h] = r;
    *(float4*)&ncs[(b * 3 + 0) * HH + h] = c1;
    *(float4*)&ncs[(b * 3 + 1) * HH + h] = c2;
    *(float4*)&ncs[(b * 3 + 2) * HH + h] = xv;
}

extern "C" void kernel_launch(void* const* d_in, const int* in_sizes, int n_in,
                              void* d_out, int out_size, void* d_ws, size_t ws_size,
                              hipStream_t stream) {
    const float* x    = (const float*)d_in[0];
    const float* cs   = (const float*)d_in[1];
    const float* rg   = (const float*)d_in[2];
    const float* Wg   = (const float*)d_in[3];
    const float* Wr   = (const float*)d_in[4];
    const float* Wo   = (const float*)d_in[5];
    const float* cw   = (const float*)d_in[6];
    const float* cb   = (const float*)d_in[7];
    const float* Wi   = (const float*)d_in[8];
    const float* Wrg  = (const float*)d_in[9];
    const float* av   = (const float*)d_in[10];

    const long BH = (long)BB * HH;
    float* out = (float*)d_out;            // [B,H]
    float* ncs = out + BH;                 // [B,3,H]
    float* nrs = out + 4 * BH;             // [B,H]

    float* ws   = (float*)d_ws;
    float* gate = ws;                      // [B,H]; bd_rglru writes h here
    float* xcio = ws + BH;                 // [B,H]; xr then xc (in place)
    u32*   wpk  = (u32*)(ws + 2 * BH);     // 16.8 MB packed-weight area
    u32*   wip  = wpk;                     // Wi packed (4.2 MB)
    u32*   wrp  = wpk + (long)NBK * HB * HB;  // Wrg packed (next 4.2 MB)

    const dim3 blk(256);
    const dim3 g1(HH / 128, BB / 128, 1);
    const dim3 g2(HB / 128, BB / 128, NBK);
    const dim3 ge((int)(BH / 4 / 256));
    const int pdense = (HH * (HH / 8) + 255) / 256;
    const int pbd    = (NBK * HB * (HB / 8) + 255) / 256;

    // 1. gate = gelu(x @ Wg^T)
    pack_w<<<pdense, blk, 0, stream>>>(Wg, wpk, HH, HH, 8);
    bgemm_pw<1><<<g1, blk, 0, stream>>>(x, wpk, gate);
    // 2. xr = x @ Wr^T
    pack_w<<<pdense, blk, 0, stream>>>(Wr, wpk, HH, HH, 8);
    bgemm_pw<0><<<g1, blk, 0, stream>>>(x, wpk, xcio);
    // 3. conv (in-place xr->xc) + state shift
    conv_kernel<<<ge, blk, 0, stream>>>(cs, cw, cb, xcio, ncs);
    // 4. fused blockdiag + RG-LRU
    pack_w<<<pbd, blk, 0, stream>>>(Wi,  wip, NBK * HB, HB, 6);
    pack_w<<<pbd, blk, 0, stream>>>(Wrg, wrp, NBK * HB, HB, 6);
    bd_rglru<<<g2, blk, 0, stream>>>(xcio, wip, wrp, rg, gate, av, nrs, gate);
    // 5. out = h @ Wo^T
    pack_w<<<pdense, blk, 0, stream>>>(Wo, wpk, HH, HH, 8);
    bgemm_pw<0><<<g1, blk, 0, stream>>>(gate, wpk, out);
}